// Round 1
// baseline (343.352 us; speedup 1.0000x reference)
//
#include <hip/hip_runtime.h>
#include <hip/hip_bf16.h>
#include <math.h>

#define B_ROWS 16384
#define NCOLS 32
#define EDIM 16
#define ACCD 512
#define NE 8
#define SBH 256
#define SBO 128
#define THD 16
#define NT 2

#define TM 64
#define KC 32
#define THR 512

// d_ws layout (floats):
//   [0, 512*256)              W1c
//   [512*256, +256*128)       W2eff
//   then one int              regul accumulator

__global__ void k_init(int* regacc) {
    if (threadIdx.x == 0) regacc[0] = 0;
}

__global__ __launch_bounds__(256) void k_w1c(const float* __restrict__ u1,
                                             const float* __restrict__ w1,
                                             const float* __restrict__ alpha1,
                                             const float* __restrict__ fce_w,
                                             float* __restrict__ W1c,
                                             int* __restrict__ regacc) {
    const int a = blockIdx.x;
    const int c = threadIdx.x;
    const float la = logf(alpha1[0]) / 0.9f;
    __shared__ int cnts[NE];
    if (c < NE) cnts[c] = 0;
    __syncthreads();
    float acc = 0.0f;
    for (int n = 0; n < NE; ++n) {
        const int idx = (a * NE + n) * SBH + c;
        const float u = u1[idx];
        const float w = w1[idx];
        const float L = logf(u) - logf(1.0f - u) + la;
        const float s = 1.0f / (1.0f + expf(-L));
        const float s_ = s * 2.1f - 0.1f;
        const float z = fminf(fmaxf(s_, 0.0f), 1.0f);
        acc += z * w * fce_w[n];
        unsigned long long m = __ballot(s_ < 0.0f);
        if ((threadIdx.x & 63) == 0) atomicAdd(&cnts[n], __popcll(m));
    }
    __syncthreads();
    W1c[a * SBH + c] = acc;
    if (c == 0) {
        int tot = 0;
        for (int n = 0; n < NE; ++n) tot += 1 - cnts[n] / NE;   // // shape[1]==8
        atomicAdd(regacc, tot);
    }
}

__global__ __launch_bounds__(128) void k_w2(const float* __restrict__ u2,
                                            const float* __restrict__ w2,
                                            const float* __restrict__ alpha2,
                                            float* __restrict__ W2eff,
                                            int* __restrict__ regacc) {
    const int c = blockIdx.x;
    const int d = threadIdx.x;
    const float la = logf(alpha2[0]) / 0.9f;
    const int idx = c * SBO + d;
    const float u = u2[idx];
    const float w = w2[idx];
    const float L = logf(u) - logf(1.0f - u) + la;
    const float s = 1.0f / (1.0f + expf(-L));
    const float s_ = s * 2.1f - 0.1f;
    const float z = fminf(fmaxf(s_, 0.0f), 1.0f);
    W2eff[idx] = z * w;
    __shared__ int cnt;
    if (d == 0) cnt = 0;
    __syncthreads();
    unsigned long long m = __ballot(s_ < 0.0f);
    if ((d & 63) == 0) atomicAdd(&cnt, __popcll(m));
    __syncthreads();
    if (d == 0) atomicAdd(regacc, 1 - cnt / SBO);               // // shape[1]==128
}

__global__ __launch_bounds__(THR) void k_main(const int* __restrict__ x,
                                              const float* __restrict__ emb,
                                              const float* __restrict__ W1c,
                                              const float* __restrict__ W2eff,
                                              const float* __restrict__ fce_b,
                                              const float* __restrict__ tw1,
                                              const float* __restrict__ tb1,
                                              const float* __restrict__ tw2,
                                              const float* __restrict__ tb2,
                                              float* __restrict__ outp) {
    __shared__ float xfs[TM][KC + 1];       // 8448 B
    __shared__ float w1s[KC][SBH];          // 32768 B
    __shared__ float tbuf[TM][SBH + 1];     // 65792 B  (reused later for o / h)

    const int tid = threadIdx.x;
    const int rowbase = blockIdx.x * TM;
    const int ty = tid >> 5;    // 0..15 -> rows ty*4..ty*4+3
    const int txx = tid & 31;   // cols: j*128 + txx*4 + u

    float acc[4][2][4];
    #pragma unroll
    for (int i = 0; i < 4; ++i)
        #pragma unroll
        for (int j = 0; j < 2; ++j)
            #pragma unroll
            for (int u = 0; u < 4; ++u) acc[i][j][u] = 0.0f;

    for (int kb = 0; kb < ACCD; kb += KC) {
        // stage gathered embedding tile  xfs[r][aa] = xf[rowbase+r][kb+aa]
        #pragma unroll
        for (int idx = tid; idx < TM * KC; idx += THR) {
            const int r = idx >> 5;
            const int aa = idx & 31;
            const int a = kb + aa;
            const int col = a >> 4;
            const int e = a & 15;
            const int xv = x[(rowbase + r) * NCOLS + col];
            xfs[r][aa] = emb[xv * EDIM + e];
        }
        // stage W1c tile
        #pragma unroll
        for (int idx = tid; idx < KC * SBH; idx += THR) {
            const int kr = idx >> 8;
            const int cc = idx & 255;
            w1s[kr][cc] = W1c[(kb + kr) * SBH + cc];
        }
        __syncthreads();
        #pragma unroll
        for (int kk = 0; kk < KC; ++kk) {
            float av[4];
            #pragma unroll
            for (int i = 0; i < 4; ++i) av[i] = xfs[ty * 4 + i][kk];
            #pragma unroll
            for (int j = 0; j < 2; ++j) {
                const float4 bv = *reinterpret_cast<const float4*>(&w1s[kk][j * 128 + txx * 4]);
                #pragma unroll
                for (int i = 0; i < 4; ++i) {
                    acc[i][j][0] += av[i] * bv.x;
                    acc[i][j][1] += av[i] * bv.y;
                    acc[i][j][2] += av[i] * bv.z;
                    acc[i][j][3] += av[i] * bv.w;
                }
            }
        }
        __syncthreads();
    }

    // t tile -> LDS
    #pragma unroll
    for (int i = 0; i < 4; ++i)
        #pragma unroll
        for (int j = 0; j < 2; ++j)
            #pragma unroll
            for (int u = 0; u < 4; ++u)
                tbuf[ty * 4 + i][j * 128 + txx * 4 + u] = acc[i][j][u];
    __syncthreads();

    // GEMM2: fce_pre[r][d] = fce_b + sum_c t[r][c] * W2eff[c][d], then relu
    {
        const int r = tid >> 3;        // 0..63
        const int dg = tid & 7;        // d = dg*16 + q
        float facc[16];
        const float fb = fce_b[0];
        #pragma unroll
        for (int q = 0; q < 16; ++q) facc[q] = fb;
        #pragma unroll 4
        for (int cc = 0; cc < SBH; ++cc) {
            const float tv = tbuf[r][cc];
            const float4* wp = reinterpret_cast<const float4*>(&W2eff[cc * SBO + dg * 16]);
            const float4 w0 = wp[0], w1v = wp[1], w2v = wp[2], w3v = wp[3];
            facc[0]  += tv * w0.x;  facc[1]  += tv * w0.y;  facc[2]  += tv * w0.z;  facc[3]  += tv * w0.w;
            facc[4]  += tv * w1v.x; facc[5]  += tv * w1v.y; facc[6]  += tv * w1v.z; facc[7]  += tv * w1v.w;
            facc[8]  += tv * w2v.x; facc[9]  += tv * w2v.y; facc[10] += tv * w2v.z; facc[11] += tv * w2v.w;
            facc[12] += tv * w3v.x; facc[13] += tv * w3v.y; facc[14] += tv * w3v.z; facc[15] += tv * w3v.w;
        }
        __syncthreads();   // all reads of tbuf done before overwrite
        float* obuf = &tbuf[0][0];     // [TM][SBO] flat
        #pragma unroll
        for (int q = 0; q < 16; ++q)
            obuf[r * SBO + dg * 16 + q] = fmaxf(facc[q], 0.0f);
    }
    __syncthreads();

    // towers
    {
        float* obuf = &tbuf[0][0];
        float* hbuf = obuf + TM * SBO;     // [TM][NT][THD]
        #pragma unroll
        for (int idx = tid; idx < TM * NT * THD; idx += THR) {
            const int r = idx >> 5;
            const int rem = idx & 31;
            const int t = rem >> 4;
            const int j = rem & 15;
            float h = tb1[t * THD + j];
            #pragma unroll 8
            for (int d = 0; d < SBO; ++d)
                h += obuf[r * SBO + d] * tw1[(t * SBO + d) * THD + j];
            hbuf[idx] = fmaxf(h, 0.0f);
        }
        __syncthreads();
        if (tid < TM * NT) {
            const int r = tid >> 1;
            const int t = tid & 1;
            float v = tb2[t];
            #pragma unroll
            for (int j = 0; j < THD; ++j)
                v += hbuf[(r * NT + t) * THD + j] * tw2[t * THD + j];
            outp[t * B_ROWS + rowbase + r] = 1.0f / (1.0f + expf(-v));
        }
    }
}

__global__ void k_final(const int* __restrict__ regacc, float* __restrict__ outp) {
    if (threadIdx.x == 0) outp[NT * B_ROWS] = 1e-4f * (float)regacc[0];
}

extern "C" void kernel_launch(void* const* d_in, const int* in_sizes, int n_in,
                              void* d_out, int out_size, void* d_ws, size_t ws_size,
                              hipStream_t stream) {
    const int*   x      = (const int*)d_in[0];
    const float* emb    = (const float*)d_in[1];
    const float* alpha1 = (const float*)d_in[2];
    const float* u1     = (const float*)d_in[3];
    const float* w1     = (const float*)d_in[4];
    const float* alpha2 = (const float*)d_in[5];
    const float* u2     = (const float*)d_in[6];
    const float* w2     = (const float*)d_in[7];
    const float* fce_w  = (const float*)d_in[8];
    const float* fce_b  = (const float*)d_in[9];
    const float* tw1    = (const float*)d_in[10];
    const float* tb1    = (const float*)d_in[11];
    const float* tw2    = (const float*)d_in[12];
    const float* tb2    = (const float*)d_in[13];
    float* outp = (float*)d_out;

    float* W1c   = (float*)d_ws;
    float* W2eff = W1c + ACCD * SBH;
    int*   regacc = (int*)(W2eff + SBH * SBO);

    k_init<<<1, 64, 0, stream>>>(regacc);
    k_w1c<<<ACCD, SBH, 0, stream>>>(u1, w1, alpha1, fce_w, W1c, regacc);
    k_w2<<<SBH, SBO, 0, stream>>>(u2, w2, alpha2, W2eff, regacc);
    k_main<<<B_ROWS / TM, THR, 0, stream>>>(x, emb, W1c, W2eff, fce_b,
                                            tw1, tb1, tw2, tb2, outp);
    k_final<<<1, 1, 0, stream>>>(regacc, outp);
}

// Round 2
// 169.457 us; speedup vs baseline: 2.0262x; 2.0262x over previous
//
#include <hip/hip_runtime.h>
#include <hip/hip_bf16.h>
#include <math.h>

#define B_ROWS 16384
#define NCOLS 32
#define EDIM 16
#define ACCD 512
#define NE 8
#define SBH 256
#define SBO 128
#define THD 16
#define NT 2

#define ROWS 32           // rows per block in k_main
#define THR 512

typedef __attribute__((ext_vector_type(8))) short bf16x8;
typedef __attribute__((ext_vector_type(4))) float f32x4;

__device__ __forceinline__ short f2bf(float f) {
    unsigned u = __float_as_uint(f);
    unsigned r = (u + 0x7FFFu + ((u >> 16) & 1u)) >> 16;   // RNE
    return (short)r;
}

// ws layout: W1cT [256][512] bf16 (256KB) | W2T [128][256] bf16 (64KB) | regparts int[768]

// ---- prep 1: hard-concrete gate + expert-collapse -> W1cT[c][a] bf16, regparts[a] ----
__global__ __launch_bounds__(256) void k_w1c(const float* __restrict__ u1,
                                             const float* __restrict__ w1,
                                             const float* __restrict__ alpha1,
                                             const float* __restrict__ fce_w,
                                             short* __restrict__ W1cT,
                                             int* __restrict__ regparts) {
    const int a = blockIdx.x;       // 0..511
    const int c = threadIdx.x;      // 0..255
    // s = sigmoid(log(u/(1-u)) + log(alpha)/beta) = u / (u + (1-u)*A), A = alpha^(-1/beta)
    const float A = expf(-logf(alpha1[0]) * (1.0f / 0.9f));
    __shared__ int cnts[NE];
    if (c < NE) cnts[c] = 0;
    __syncthreads();
    float acc = 0.0f;
    #pragma unroll
    for (int n = 0; n < NE; ++n) {
        const int idx = (a * NE + n) * SBH + c;
        const float u = u1[idx];
        const float w = w1[idx];
        const float s = u / (u + (1.0f - u) * A);
        const float s_ = s * 2.1f - 0.1f;
        const float z = fminf(fmaxf(s_, 0.0f), 1.0f);
        acc += z * w * fce_w[n];
        unsigned long long m = __ballot(s_ < 0.0f);
        if ((c & 63) == 0) atomicAdd(&cnts[n], __popcll(m));
    }
    __syncthreads();
    W1cT[c * ACCD + a] = f2bf(acc);
    if (c == 0) {
        int tot = 0;
        #pragma unroll
        for (int n = 0; n < NE; ++n) tot += 1 - cnts[n] / NE;   // // shape[1]==8
        regparts[a] = tot;
    }
}

// ---- prep 2: gate2 -> W2T[d][c] bf16, regparts[512+c] ----
__global__ __launch_bounds__(128) void k_w2(const float* __restrict__ u2,
                                            const float* __restrict__ w2,
                                            const float* __restrict__ alpha2,
                                            short* __restrict__ W2T,
                                            int* __restrict__ regparts) {
    const int c = blockIdx.x;       // 0..255
    const int d = threadIdx.x;      // 0..127
    const float A = expf(-logf(alpha2[0]) * (1.0f / 0.9f));
    const int idx = c * SBO + d;
    const float u = u2[idx];
    const float w = w2[idx];
    const float s = u / (u + (1.0f - u) * A);
    const float s_ = s * 2.1f - 0.1f;
    const float z = fminf(fmaxf(s_, 0.0f), 1.0f);
    W2T[d * SBH + c] = f2bf(z * w);
    __shared__ int cnt;
    if (d == 0) cnt = 0;
    __syncthreads();
    unsigned long long m = __ballot(s_ < 0.0f);
    if ((d & 63) == 0) atomicAdd(&cnt, __popcll(m));
    __syncthreads();
    if (d == 0) regparts[ACCD + c] = 1 - cnt / SBO;              // // shape[1]==128
}

// ---- main fused kernel: gather -> MFMA GEMM1 -> MFMA GEMM2 -> towers ----
__global__ __launch_bounds__(THR, 4) void k_main(const int* __restrict__ x,
                                                 const float* __restrict__ emb,
                                                 const short* __restrict__ W1cT,
                                                 const short* __restrict__ W2T,
                                                 const float* __restrict__ fce_b,
                                                 const float* __restrict__ tw1,
                                                 const float* __restrict__ tb1,
                                                 const float* __restrict__ tw2,
                                                 const float* __restrict__ tb2,
                                                 const int* __restrict__ regparts,
                                                 float* __restrict__ outp) {
    __shared__ float tls[ROWS][260];          // t tile fp32, padded stride (bank stagger); aliased as o[32][132] later
    __shared__ float hbuf[ROWS * NT * THD];   // 4 KB

    const int tid = threadIdx.x;
    const int l = tid & 63;
    const int w = tid >> 6;            // wave 0..7
    const int lrow = l & 15;
    const int lg = l >> 4;             // 0..3
    const int rowbase = blockIdx.x * ROWS;

    // ---------------- GEMM1: t[32][256] = xf[32][512] x W1c[512][256] ----------------
    {
        const int wr = w >> 2;         // 0..1  (16-row tile)
        const int wcg = w & 3;         // 0..3  (64-col group, 4 frags)
        const int grow = rowbase + wr * 16 + lrow;
        const int* xrow = x + grow * NCOLS;

        f32x4 acc[4];
        #pragma unroll
        for (int fc = 0; fc < 4; ++fc) acc[fc] = (f32x4){0.f, 0.f, 0.f, 0.f};

        #pragma unroll 4
        for (int kc = 0; kc < 16; ++kc) {
            // A fragment: xf[grow][kc*32 + lg*8 .. +8] == emb[x[grow][col]][e0..e0+7]
            const int col = kc * 2 + (lg >> 1);
            const int e0 = (lg & 1) * 8;
            const int xv = xrow[col];
            const float4* ep = reinterpret_cast<const float4*>(emb + (size_t)xv * EDIM + e0);
            const float4 f0 = ep[0], f1 = ep[1];
            bf16x8 afr;
            afr[0] = f2bf(f0.x); afr[1] = f2bf(f0.y); afr[2] = f2bf(f0.z); afr[3] = f2bf(f0.w);
            afr[4] = f2bf(f1.x); afr[5] = f2bf(f1.y); afr[6] = f2bf(f1.z); afr[7] = f2bf(f1.w);
            #pragma unroll
            for (int fc = 0; fc < 4; ++fc) {
                const int c = wcg * 64 + fc * 16 + lrow;
                const bf16x8 bfr = *reinterpret_cast<const bf16x8*>(W1cT + c * ACCD + kc * 32 + lg * 8);
                acc[fc] = __builtin_amdgcn_mfma_f32_16x16x32_bf16(afr, bfr, acc[fc], 0, 0, 0);
            }
        }
        // D layout: col = l&15, row = lg*4 + reg
        #pragma unroll
        for (int fc = 0; fc < 4; ++fc)
            #pragma unroll
            for (int r = 0; r < 4; ++r)
                tls[wr * 16 + lg * 4 + r][wcg * 64 + fc * 16 + lrow] = acc[fc][r];
    }
    __syncthreads();

    // ---------------- GEMM2: o[32][128] = t[32][256] x W2eff[256][128], +fce_b, relu ----------------
    f32x4 acc2[2];
    {
        const int wr2 = w >> 2;        // 0..1
        const int wd = w & 3;          // 0..3 (32-d group, 2 frags)
        acc2[0] = (f32x4){0.f, 0.f, 0.f, 0.f};
        acc2[1] = (f32x4){0.f, 0.f, 0.f, 0.f};
        const int r2 = wr2 * 16 + lrow;
        #pragma unroll
        for (int kc = 0; kc < 8; ++kc) {
            const float* tp = &tls[r2][kc * 32 + lg * 8];
            const float4 t0 = *reinterpret_cast<const float4*>(tp);
            const float4 t1 = *reinterpret_cast<const float4*>(tp + 4);
            bf16x8 afr;
            afr[0] = f2bf(t0.x); afr[1] = f2bf(t0.y); afr[2] = f2bf(t0.z); afr[3] = f2bf(t0.w);
            afr[4] = f2bf(t1.x); afr[5] = f2bf(t1.y); afr[6] = f2bf(t1.z); afr[7] = f2bf(t1.w);
            #pragma unroll
            for (int fd = 0; fd < 2; ++fd) {
                const int d = wd * 32 + fd * 16 + lrow;
                const bf16x8 bfr = *reinterpret_cast<const bf16x8*>(W2T + d * SBH + kc * 32 + lg * 8);
                acc2[fd] = __builtin_amdgcn_mfma_f32_16x16x32_bf16(afr, bfr, acc2[fd], 0, 0, 0);
            }
        }
    }
    __syncthreads();   // all tls reads done before aliasing as o
    {
        const int wr2 = w >> 2;
        const int wd = w & 3;
        const float fb = fce_b[0];
        float* ols = &tls[0][0];       // o[32][132]
        #pragma unroll
        for (int fd = 0; fd < 2; ++fd)
            #pragma unroll
            for (int r = 0; r < 4; ++r) {
                const int row = wr2 * 16 + lg * 4 + r;
                const int d = wd * 32 + fd * 16 + lrow;
                ols[row * 132 + d] = fmaxf(acc2[fd][r] + fb, 0.0f);
            }
    }
    __syncthreads();

    // ---------------- towers ----------------
    {
        const float* ols = &tls[0][0];
        for (int idx = tid; idx < ROWS * NT * THD; idx += THR) {
            const int r = idx >> 5;
            const int t = (idx >> 4) & 1;
            const int j = idx & 15;
            float h = tb1[t * THD + j];
            #pragma unroll 8
            for (int d = 0; d < SBO; ++d)
                h += ols[r * 132 + d] * tw1[(t * SBO + d) * THD + j];
            hbuf[idx] = fmaxf(h, 0.0f);
        }
    }
    __syncthreads();
    if (tid < ROWS * NT) {
        const int r = tid >> 1;
        const int t = tid & 1;
        float v = tb2[t];
        #pragma unroll
        for (int j = 0; j < THD; ++j)
            v += hbuf[r * (NT * THD) + t * THD + j] * tw2[t * THD + j];
        outp[t * B_ROWS + rowbase + r] = 1.0f / (1.0f + expf(-v));
    }

    // ---------------- regularizer (block 0 only) ----------------
    if (blockIdx.x == 0 && tid < 64) {
        int s = 0;
        for (int i = tid; i < ACCD + SBH; i += 64) s += regparts[i];
        #pragma unroll
        for (int off = 32; off > 0; off >>= 1) s += __shfl_down(s, off);
        if (tid == 0) outp[NT * B_ROWS] = 1e-4f * (float)s;
    }
}

extern "C" void kernel_launch(void* const* d_in, const int* in_sizes, int n_in,
                              void* d_out, int out_size, void* d_ws, size_t ws_size,
                              hipStream_t stream) {
    const int*   x      = (const int*)d_in[0];
    const float* emb    = (const float*)d_in[1];
    const float* alpha1 = (const float*)d_in[2];
    const float* u1     = (const float*)d_in[3];
    const float* w1     = (const float*)d_in[4];
    const float* alpha2 = (const float*)d_in[5];
    const float* u2     = (const float*)d_in[6];
    const float* w2     = (const float*)d_in[7];
    const float* fce_w  = (const float*)d_in[8];
    const float* fce_b  = (const float*)d_in[9];
    const float* tw1    = (const float*)d_in[10];
    const float* tb1    = (const float*)d_in[11];
    const float* tw2    = (const float*)d_in[12];
    const float* tb2    = (const float*)d_in[13];
    float* outp = (float*)d_out;

    short* W1cT = (short*)d_ws;                      // [256][512] bf16
    short* W2T  = W1cT + SBH * ACCD;                 // [128][256] bf16
    int*   regparts = (int*)(W2T + SBO * SBH);       // [768]

    k_w1c<<<ACCD, SBH, 0, stream>>>(u1, w1, alpha1, fce_w, W1cT, regparts);
    k_w2<<<SBH, SBO, 0, stream>>>(u2, w2, alpha2, W2T, regparts);
    k_main<<<B_ROWS / ROWS, THR, 0, stream>>>(x, emb, W1cT, W2T, fce_b,
                                              tw1, tb1, tw2, tb2, regparts, outp);
}

// Round 3
// 140.148 us; speedup vs baseline: 2.4499x; 1.2091x over previous
//
#include <hip/hip_runtime.h>
#include <hip/hip_bf16.h>
#include <math.h>

#define B_ROWS 16384
#define NCOLS 32
#define EDIM 16
#define ACCD 512
#define NE 8
#define SBH 256
#define SBO 128
#define THD 16
#define NT 2

#define ROWS 32
#define THR 512

typedef __attribute__((ext_vector_type(8))) short bf16x8;
typedef __attribute__((ext_vector_type(4))) float f32x4;
typedef __attribute__((ext_vector_type(16))) float f32x16;

__device__ __forceinline__ short f2bf(float f) {
    unsigned u = __float_as_uint(f);
    unsigned r = (u + 0x7FFFu + ((u >> 16) & 1u)) >> 16;   // RNE
    return (short)r;
}

__device__ __forceinline__ bf16x8 pack8(float4 a, float4 b) {
    bf16x8 v;
    v[0] = f2bf(a.x); v[1] = f2bf(a.y); v[2] = f2bf(a.z); v[3] = f2bf(a.w);
    v[4] = f2bf(b.x); v[5] = f2bf(b.y); v[6] = f2bf(b.z); v[7] = f2bf(b.w);
    return v;
}

// ws: W1cT[256][512] bf16 (256KB) | W2T[128][256] bf16 (64KB) | tw1T[32][128] bf16 (8KB) | regparts int[768]

// ---- single prep kernel: blocks 0..511 gate1+collapse, 512..639 gate2, 640 tw1 transpose ----
__global__ __launch_bounds__(256) void k_prep(const float* __restrict__ u1,
                                              const float* __restrict__ w1,
                                              const float* __restrict__ alpha1,
                                              const float* __restrict__ fce_w,
                                              const float* __restrict__ u2,
                                              const float* __restrict__ w2,
                                              const float* __restrict__ alpha2,
                                              const float* __restrict__ tw1,
                                              short* __restrict__ W1cT,
                                              short* __restrict__ W2T,
                                              short* __restrict__ tw1T,
                                              int* __restrict__ regparts) {
    const int bid = blockIdx.x;
    const int tid = threadIdx.x;
    if (bid < 512) {
        const int a = bid, c = tid;
        const float A = expf(-logf(alpha1[0]) * (1.0f / 0.9f));
        __shared__ int cnts[NE];
        if (c < NE) cnts[c] = 0;
        __syncthreads();
        float acc = 0.0f;
        #pragma unroll
        for (int n = 0; n < NE; ++n) {
            const int idx = (a * NE + n) * SBH + c;
            const float u = u1[idx];
            const float s = u / (u + (1.0f - u) * A);
            const float s_ = s * 2.1f - 0.1f;
            const float z = fminf(fmaxf(s_, 0.0f), 1.0f);
            acc += z * w1[idx] * fce_w[n];
            unsigned long long m = __ballot(s_ < 0.0f);
            if ((c & 63) == 0) atomicAdd(&cnts[n], __popcll(m));
        }
        __syncthreads();
        W1cT[c * ACCD + a] = f2bf(acc);
        if (c == 0) {
            int tot = 0;
            #pragma unroll
            for (int n = 0; n < NE; ++n) tot += 1 - cnts[n] / NE;   // // NE (shape[1])
            regparts[a] = tot;
        }
    } else if (bid < 640) {
        const int c = (bid - 512) * 2 + (tid >> 7);
        const int d = tid & 127;
        const float A = expf(-logf(alpha2[0]) * (1.0f / 0.9f));
        const int idx = c * SBO + d;
        const float u = u2[idx];
        const float s = u / (u + (1.0f - u) * A);
        const float s_ = s * 2.1f - 0.1f;
        const float z = fminf(fmaxf(s_, 0.0f), 1.0f);
        W2T[d * SBH + c] = f2bf(z * w2[idx]);
        __shared__ int cnts2[2];
        if (tid < 2) cnts2[tid] = 0;
        __syncthreads();
        unsigned long long m = __ballot(s_ < 0.0f);
        if ((tid & 63) == 0) atomicAdd(&cnts2[tid >> 7], __popcll(m));
        __syncthreads();
        if ((tid & 127) == 0) regparts[ACCD + c] = 1 - cnts2[tid >> 7] / SBO;  // // SBO
    } else {
        #pragma unroll
        for (int i = 0; i < 16; ++i) {
            const int e = tid * 16 + i;          // 4096 = 32*128
            const int jj = e >> 7;               // t*16+j
            const int d = e & 127;
            tw1T[jj * SBO + d] = f2bf(tw1[((jj >> 4) * SBO + d) * THD + (jj & 15)]);
        }
    }
}

// ---- fused main: stage xf (bf16, swizzled) -> 32x32x16 MFMA GEMM1 -> GEMM2 -> MFMA towers ----
__global__ __launch_bounds__(THR, 4) void k_main(const int* __restrict__ x,
                                                 const float* __restrict__ emb,
                                                 const short* __restrict__ W1cT,
                                                 const short* __restrict__ W2T,
                                                 const short* __restrict__ tw1T,
                                                 const float* __restrict__ fce_b,
                                                 const float* __restrict__ tb1,
                                                 const float* __restrict__ tw2,
                                                 const float* __restrict__ tb2,
                                                 const int* __restrict__ regparts,
                                                 float* __restrict__ outp) {
    __shared__ __align__(16) char lds[32768];   // [0,16K): xf half (later o), [16K,32K): t
    char* xfb = lds;
    char* tbuf = lds + 16384;
    char* ob = lds;                              // o aliases xf after GEMM1 done

    const int tid = threadIdx.x;
    const int l = tid & 63;
    const int w = tid >> 6;
    const int rowbase = blockIdx.x * ROWS;
    const int lrow32 = l & 31;
    const int hg = l >> 5;
    const int lrow16 = l & 15;
    const int lg4 = (l >> 4) & 3;

    // staging roles: one emb row (64B) per thread per half
    const int srow = tid >> 4;       // 0..31
    const int sseg = tid & 15;       // 0..15 (one x-col each)
    const int sswz = (srow & 15) << 4;
    char* sbase = xfb + (srow << 9);

    // GEMM1 A-read roles (32x32x16): row = l&31, k = hg*8+j
    char* abase = xfb + (lrow32 << 9);
    const int aswz = (lrow32 & 15) << 4;

    f32x16 acc;
    #pragma unroll
    for (int i = 0; i < 16; ++i) acc[i] = 0.0f;

    for (int kb = 0; kb < 2; ++kb) {
        {   // stage this K-half: xf[srow][sseg*16..+16) = emb[x[srow][kb*16+sseg]][:]
            const int xv = x[(rowbase + srow) * NCOLS + kb * 16 + sseg];
            const float4* ep = reinterpret_cast<const float4*>(emb + (size_t)xv * EDIM);
            const float4 e0 = ep[0], e1 = ep[1], e2 = ep[2], e3 = ep[3];
            *(bf16x8*)(sbase + ((sseg * 32 + 0) ^ sswz))  = pack8(e0, e1);
            *(bf16x8*)(sbase + ((sseg * 32 + 16) ^ sswz)) = pack8(e2, e3);
        }
        __syncthreads();
        // GEMM1 half: wave w owns cols w*32..+31
        const short* bptr = W1cT + (w * 32 + lrow32) * ACCD + kb * 256 + hg * 8;
        #pragma unroll
        for (int kc = 0; kc < 16; ++kc) {
            const bf16x8 av = *(const bf16x8*)(abase + ((kc * 32 + hg * 16) ^ aswz));
            const bf16x8 bv = *(const bf16x8*)(bptr + kc * 16);
            acc = __builtin_amdgcn_mfma_f32_32x32x16_bf16(av, bv, acc, 0, 0, 0);
        }
        __syncthreads();   // xf reads done before restage / before o aliasing
    }

    // t-tile write (bf16, swizzled). D(32x32): col=l&31, row=(r&3)+8*(r>>2)+4*hg
    {
        const int tcol2 = (w * 32 + lrow32) * 2;
        #pragma unroll
        for (int r = 0; r < 16; ++r) {
            const int trow = (r & 3) + 8 * (r >> 2) + 4 * hg;
            *(short*)(tbuf + (trow << 9) + (tcol2 ^ ((trow & 15) << 4))) = f2bf(acc[r]);
        }
    }
    __syncthreads();

    // GEMM2 (16x16x32): wave w: rows (w>>2)*16..+15, cols (w&3)*32..+31 (2 frags)
    f32x4 acc2[2];
    acc2[0] = (f32x4){0.f, 0.f, 0.f, 0.f};
    acc2[1] = (f32x4){0.f, 0.f, 0.f, 0.f};
    {
        const int rA = (w >> 2) * 16 + lrow16;
        char* tAb = tbuf + (rA << 9);
        const int tswz = (rA & 15) << 4;
        const short* b2p = W2T + ((w & 3) * 32 + lrow16) * SBH + lg4 * 8;
        #pragma unroll
        for (int kc = 0; kc < 8; ++kc) {
            const bf16x8 av = *(const bf16x8*)(tAb + ((kc * 64 + lg4 * 16) ^ tswz));
            const bf16x8 b0 = *(const bf16x8*)(b2p + kc * 32);
            const bf16x8 b1 = *(const bf16x8*)(b2p + 16 * SBH + kc * 32);
            acc2[0] = __builtin_amdgcn_mfma_f32_16x16x32_bf16(av, b0, acc2[0], 0, 0, 0);
            acc2[1] = __builtin_amdgcn_mfma_f32_16x16x32_bf16(av, b1, acc2[1], 0, 0, 0);
        }
    }
    // o write (relu + fce_b), bf16 swizzled into xf region (safe: xf dead since last barrier)
    {
        const float fb = fce_b[0];
        const int rt2 = w >> 2, cg = w & 3;
        #pragma unroll
        for (int fd = 0; fd < 2; ++fd) {
            const int d2 = (cg * 32 + fd * 16 + lrow16) * 2;
            #pragma unroll
            for (int rr = 0; rr < 4; ++rr) {
                const int orow = rt2 * 16 + lg4 * 4 + rr;
                const float v = fmaxf(acc2[fd][rr] + fb, 0.0f);
                *(short*)(ob + (orow << 8) + (d2 ^ ((orow & 15) << 4))) = f2bf(v);
            }
        }
    }
    __syncthreads();

    // towers: waves 0..3: rtt=w>>1 rows, ct=w&1 task. h = relu(o @ tw1T^T + tb1); out = sigmoid(h·tw2+tb2)
    if (w < 4) {
        const int rtt = w >> 1, ct = w & 1;
        f32x4 h = (f32x4){0.f, 0.f, 0.f, 0.f};
        char* oAb = ob + ((rtt * 16 + lrow16) << 8);
        const int oswz = ((rtt * 16 + lrow16) & 15) << 4;
        const short* bT = tw1T + (ct * 16 + lrow16) * SBO + lg4 * 8;
        #pragma unroll
        for (int kc = 0; kc < 4; ++kc) {
            const bf16x8 av = *(const bf16x8*)(oAb + ((kc * 64 + lg4 * 16) ^ oswz));
            const bf16x8 bv = *(const bf16x8*)(bT + kc * 32);
            h = __builtin_amdgcn_mfma_f32_16x16x32_bf16(av, bv, h, 0, 0, 0);
        }
        const float b1v = tb1[ct * THD + lrow16];
        const float w2v = tw2[ct * THD + lrow16];
        float p[4];
        #pragma unroll
        for (int rr = 0; rr < 4; ++rr) {
            p[rr] = fmaxf(h[rr] + b1v, 0.0f) * w2v;
            #pragma unroll
            for (int off = 8; off >= 1; off >>= 1)
                p[rr] += __shfl_xor(p[rr], off);
        }
        if (lrow16 == 0) {
            const float b2v = tb2[ct];
            #pragma unroll
            for (int rr = 0; rr < 4; ++rr) {
                const int rowo = rtt * 16 + lg4 * 4 + rr;
                outp[ct * B_ROWS + rowbase + rowo] = 1.0f / (1.0f + __expf(-(p[rr] + b2v)));
            }
        }
    }

    // regularizer (block 0)
    if (blockIdx.x == 0 && tid < 64) {
        int s = 0;
        for (int i = tid; i < ACCD + SBH; i += 64) s += regparts[i];
        #pragma unroll
        for (int off = 32; off > 0; off >>= 1) s += __shfl_down(s, off);
        if (tid == 0) outp[NT * B_ROWS] = 1e-4f * (float)s;
    }
}

extern "C" void kernel_launch(void* const* d_in, const int* in_sizes, int n_in,
                              void* d_out, int out_size, void* d_ws, size_t ws_size,
                              hipStream_t stream) {
    const int*   x      = (const int*)d_in[0];
    const float* emb    = (const float*)d_in[1];
    const float* alpha1 = (const float*)d_in[2];
    const float* u1     = (const float*)d_in[3];
    const float* w1     = (const float*)d_in[4];
    const float* alpha2 = (const float*)d_in[5];
    const float* u2     = (const float*)d_in[6];
    const float* w2     = (const float*)d_in[7];
    const float* fce_w  = (const float*)d_in[8];
    const float* fce_b  = (const float*)d_in[9];
    const float* tw1    = (const float*)d_in[10];
    const float* tb1    = (const float*)d_in[11];
    const float* tw2    = (const float*)d_in[12];
    const float* tb2    = (const float*)d_in[13];
    float* outp = (float*)d_out;

    short* W1cT = (short*)d_ws;                       // [256][512]
    short* W2T  = W1cT + SBH * ACCD;                  // [128][256]
    short* tw1T = W2T + SBO * SBH;                    // [32][128]
    int*   regparts = (int*)(tw1T + NT * THD * SBO);  // [768]

    k_prep<<<641, 256, 0, stream>>>(u1, w1, alpha1, fce_w, u2, w2, alpha2, tw1,
                                    W1cT, W2T, tw1T, regparts);
    k_main<<<B_ROWS / ROWS, THR, 0, stream>>>(x, emb, W1cT, W2T, tw1T, fce_b,
                                              tb1, tw2, tb2, regparts, outp);
}

// Round 4
// 126.386 us; speedup vs baseline: 2.7167x; 1.1089x over previous
//
#include <hip/hip_runtime.h>
#include <hip/hip_bf16.h>
#include <math.h>

#define B_ROWS 16384
#define NCOLS 32
#define EDIM 16
#define ACCD 512
#define NE 8
#define SBH 256
#define SBO 128
#define THD 16
#define NT 2

#define ROWS 64
#define THR 512

typedef __attribute__((ext_vector_type(8))) short bf16x8;
typedef __attribute__((ext_vector_type(4))) float f32x4;
typedef __attribute__((ext_vector_type(16))) float f32x16;

__device__ __forceinline__ short f2bf(float f) {
    unsigned u = __float_as_uint(f);
    unsigned r = (u + 0x7FFFu + ((u >> 16) & 1u)) >> 16;   // RNE
    return (short)r;
}

__device__ __forceinline__ bf16x8 pack8(float4 a, float4 b) {
    bf16x8 v;
    v[0] = f2bf(a.x); v[1] = f2bf(a.y); v[2] = f2bf(a.z); v[3] = f2bf(a.w);
    v[4] = f2bf(b.x); v[5] = f2bf(b.y); v[6] = f2bf(b.z); v[7] = f2bf(b.w);
    return v;
}

// ws: W1cF 256KB bf16 fragment-linear | W2F 64KB bf16 fragment-linear |
//     tw1T [32][128] bf16 | regparts int[768]
// W1cF frag (ks 0..31, cg 0..7): lane l -> col=cg*32+(l&31), k=ks*16+(l>>5)*8+j
// W2F  frag (ks 0..15, cg 0..3): lane l -> col=cg*32+(l&31), k=ks*16+(l>>5)*8+j

__global__ __launch_bounds__(256) void k_prep(const float* __restrict__ u1,
                                              const float* __restrict__ w1,
                                              const float* __restrict__ alpha1,
                                              const float* __restrict__ fce_w,
                                              const float* __restrict__ u2,
                                              const float* __restrict__ w2,
                                              const float* __restrict__ alpha2,
                                              const float* __restrict__ tw1,
                                              short* __restrict__ W1cF,
                                              short* __restrict__ W2F,
                                              short* __restrict__ tw1T,
                                              int* __restrict__ regparts) {
    const int bid = blockIdx.x;
    const int tid = threadIdx.x;
    if (bid < 512) {
        const int a = bid, c = tid;         // a = k-index, c = col
        const float A = expf(-logf(alpha1[0]) * (1.0f / 0.9f));
        __shared__ int cnts[NE];
        if (c < NE) cnts[c] = 0;
        __syncthreads();
        float acc = 0.0f;
        #pragma unroll
        for (int n = 0; n < NE; ++n) {
            const int idx = (a * NE + n) * SBH + c;
            const float u = u1[idx];
            const float s = u / (u + (1.0f - u) * A);
            const float s_ = s * 2.1f - 0.1f;
            const float z = fminf(fmaxf(s_, 0.0f), 1.0f);
            acc += z * w1[idx] * fce_w[n];
            unsigned long long m = __ballot(s_ < 0.0f);
            if ((c & 63) == 0) atomicAdd(&cnts[n], __popcll(m));
        }
        __syncthreads();
        {
            const int ks = a >> 4, kr = a & 15;
            const int sub = kr >> 3, j = kr & 7;
            const int cg = c >> 5, lane = (sub << 5) | (c & 31);
            W1cF[(((ks * 8 + cg) * 64) + lane) * 8 + j] = f2bf(acc);
        }
        if (c == 0) {
            int tot = 0;
            #pragma unroll
            for (int n = 0; n < NE; ++n) tot += 1 - cnts[n] / NE;   // // NE (shape[1])
            regparts[a] = tot;
        }
    } else if (bid < 640) {
        const int c = (bid - 512) * 2 + (tid >> 7);   // k-index 0..255
        const int d = tid & 127;                      // col
        const float A = expf(-logf(alpha2[0]) * (1.0f / 0.9f));
        const int idx = c * SBO + d;
        const float u = u2[idx];
        const float s = u / (u + (1.0f - u) * A);
        const float s_ = s * 2.1f - 0.1f;
        const float z = fminf(fmaxf(s_, 0.0f), 1.0f);
        {
            const int ks = c >> 4, kr = c & 15;
            const int sub = kr >> 3, j = kr & 7;
            const int cg = d >> 5, lane = (sub << 5) | (d & 31);
            W2F[(((ks * 4 + cg) * 64) + lane) * 8 + j] = f2bf(z * w2[idx]);
        }
        __shared__ int cnts2[2];
        if (tid < 2) cnts2[tid] = 0;
        __syncthreads();
        unsigned long long m = __ballot(s_ < 0.0f);
        if ((tid & 63) == 0) atomicAdd(&cnts2[tid >> 7], __popcll(m));
        __syncthreads();
        if ((tid & 127) == 0) regparts[ACCD + c] = 1 - cnts2[tid >> 7] / SBO;  // // SBO
    } else {
        #pragma unroll
        for (int i = 0; i < 16; ++i) {
            const int e = tid * 16 + i;          // 4096 = 32*128
            const int jj = e >> 7;               // t*16+j
            const int d = e & 127;
            tw1T[jj * SBO + d] = f2bf(tw1[((jj >> 4) * SBO + d) * THD + (jj & 15)]);
        }
    }
}

#define MFMA32(a, b, c) __builtin_amdgcn_mfma_f32_32x32x16_bf16((a), (b), (c), 0, 0, 0)

__global__ __launch_bounds__(THR, 2) void k_main(const int* __restrict__ x,
                                                 const float* __restrict__ emb,
                                                 const short* __restrict__ W1cF,
                                                 const short* __restrict__ W2F,
                                                 const short* __restrict__ tw1T,
                                                 const float* __restrict__ fce_b,
                                                 const float* __restrict__ tb1,
                                                 const float* __restrict__ tw2,
                                                 const float* __restrict__ tb2,
                                                 const int* __restrict__ regparts,
                                                 float* __restrict__ outp) {
    // LDS: A[64][512] bf16 = 64KB at [0,64K).  After GEMM1: t[64][256] bf16 aliases [0,32K).
    // After GEMM2: o[64][128] bf16 aliases [32K,48K).
    __shared__ __align__(16) char lds[65536];

    const int tid = threadIdx.x;
    const int l = tid & 63;
    const int w = tid >> 6;
    const int lrow32 = l & 31;
    const int hg = l >> 5;
    const int lrow16 = l & 15;
    const int lg4 = (l >> 4) & 3;
    const int rowbase = blockIdx.x * ROWS;

    // ---- stage A: 64 rows x 512 k (bf16, XOR-swizzled), 4 emb rows per thread ----
    {
        const int r0 = tid >> 3;             // 0..63
        const int cb = (tid & 7) * 4;        // col base
        const int4 xv4 = *reinterpret_cast<const int4*>(x + (rowbase + r0) * NCOLS + cb);
        char* rbase = lds + (r0 << 10);
        const int swz = (r0 & 15) << 4;
        int xs[4] = {xv4.x, xv4.y, xv4.z, xv4.w};
        #pragma unroll
        for (int i = 0; i < 4; ++i) {
            const float4* ep = reinterpret_cast<const float4*>(emb + (size_t)xs[i] * EDIM);
            const float4 e0 = ep[0], e1 = ep[1], e2 = ep[2], e3 = ep[3];
            *(bf16x8*)(rbase + ((((cb + i) * 32) + 0) ^ swz))  = pack8(e0, e1);
            *(bf16x8*)(rbase + ((((cb + i) * 32) + 16) ^ swz)) = pack8(e2, e3);
        }
    }
    __syncthreads();

    // ---- GEMM1: t[64][256] = xf[64][512] x W1c[512][256]; wave: rg=w>>2 rows, cols (w&3)*64+{0,32} ----
    const int rg = w >> 2;
    const int cgp = (w & 3) * 2;
    f32x16 acc0, acc1;
    #pragma unroll
    for (int i = 0; i < 16; ++i) { acc0[i] = 0.0f; acc1[i] = 0.0f; }
    {
        char* aAb = lds + ((rg * 32 + lrow32) << 10);
        const int aswz = (lrow32 & 15) << 4;
        const bf16x8* Bp = ((const bf16x8*)W1cF) + l;

        bf16x8 p0a = Bp[(0 * 8 + cgp) * 64], p0b = Bp[(0 * 8 + cgp + 1) * 64];
        bf16x8 p1a = Bp[(1 * 8 + cgp) * 64], p1b = Bp[(1 * 8 + cgp + 1) * 64];
        bf16x8 p2a = Bp[(2 * 8 + cgp) * 64], p2b = Bp[(2 * 8 + cgp + 1) * 64];
        bf16x8 p3a = Bp[(3 * 8 + cgp) * 64], p3b = Bp[(3 * 8 + cgp + 1) * 64];

        #pragma unroll
        for (int ks = 0; ks < 32; ks += 4) {
            {
                const bf16x8 a = *(const bf16x8*)(aAb + ((((ks + 0) * 32) + hg * 16) ^ aswz));
                acc0 = MFMA32(a, p0a, acc0);
                acc1 = MFMA32(a, p0b, acc1);
                if (ks + 4 < 32) { p0a = Bp[((ks + 4) * 8 + cgp) * 64]; p0b = Bp[((ks + 4) * 8 + cgp + 1) * 64]; }
            }
            {
                const bf16x8 a = *(const bf16x8*)(aAb + ((((ks + 1) * 32) + hg * 16) ^ aswz));
                acc0 = MFMA32(a, p1a, acc0);
                acc1 = MFMA32(a, p1b, acc1);
                if (ks + 5 < 32) { p1a = Bp[((ks + 5) * 8 + cgp) * 64]; p1b = Bp[((ks + 5) * 8 + cgp + 1) * 64]; }
            }
            {
                const bf16x8 a = *(const bf16x8*)(aAb + ((((ks + 2) * 32) + hg * 16) ^ aswz));
                acc0 = MFMA32(a, p2a, acc0);
                acc1 = MFMA32(a, p2b, acc1);
                if (ks + 6 < 32) { p2a = Bp[((ks + 6) * 8 + cgp) * 64]; p2b = Bp[((ks + 6) * 8 + cgp + 1) * 64]; }
            }
            {
                const bf16x8 a = *(const bf16x8*)(aAb + ((((ks + 3) * 32) + hg * 16) ^ aswz));
                acc0 = MFMA32(a, p3a, acc0);
                acc1 = MFMA32(a, p3b, acc1);
                if (ks + 7 < 32) { p3a = Bp[((ks + 7) * 8 + cgp) * 64]; p3b = Bp[((ks + 7) * 8 + cgp + 1) * 64]; }
            }
        }
    }
    __syncthreads();   // all A reads done; safe to alias t onto [0,32K)

    // ---- t write (bf16 swizzled). D(32x32): col=l&31, row=(r&3)+8*(r>>2)+4*hg ----
    {
        #pragma unroll
        for (int r = 0; r < 16; ++r) {
            const int trow = rg * 32 + (r & 3) + 8 * (r >> 2) + 4 * hg;
            const int sw = (trow & 15) << 4;
            *(short*)(lds + (trow << 9) + ((((cgp * 32 + lrow32) * 2)) ^ sw)) = f2bf(acc0[r]);
            *(short*)(lds + (trow << 9) + (((((cgp + 1) * 32 + lrow32) * 2)) ^ sw)) = f2bf(acc1[r]);
        }
    }

    // ---- GEMM2: o[64][128] = t[64][256] x W2eff[256][128]; wave: rg2=w>>2 rows, cg2=w&3 cols ----
    const int cg2 = w & 3;
    f32x16 acc2;
    #pragma unroll
    for (int i = 0; i < 16; ++i) acc2[i] = 0.0f;
    {
        const bf16x8* Bp2 = ((const bf16x8*)W2F) + l;
        bf16x8 q0 = Bp2[(0 * 4 + cg2) * 64];
        bf16x8 q1 = Bp2[(1 * 4 + cg2) * 64];
        bf16x8 q2 = Bp2[(2 * 4 + cg2) * 64];
        bf16x8 q3 = Bp2[(3 * 4 + cg2) * 64];
        __syncthreads();   // t complete (q prefetch overlapped with t writes)
        char* tAb = lds + ((rg * 32 + lrow32) << 9);
        const int tswz = (lrow32 & 15) << 4;
        #pragma unroll
        for (int ks = 0; ks < 16; ks += 4) {
            {
                const bf16x8 a = *(const bf16x8*)(tAb + ((((ks + 0) * 32) + hg * 16) ^ tswz));
                acc2 = MFMA32(a, q0, acc2);
                if (ks + 4 < 16) q0 = Bp2[((ks + 4) * 4 + cg2) * 64];
            }
            {
                const bf16x8 a = *(const bf16x8*)(tAb + ((((ks + 1) * 32) + hg * 16) ^ tswz));
                acc2 = MFMA32(a, q1, acc2);
                if (ks + 5 < 16) q1 = Bp2[((ks + 5) * 4 + cg2) * 64];
            }
            {
                const bf16x8 a = *(const bf16x8*)(tAb + ((((ks + 2) * 32) + hg * 16) ^ tswz));
                acc2 = MFMA32(a, q2, acc2);
                if (ks + 6 < 16) q2 = Bp2[((ks + 6) * 4 + cg2) * 64];
            }
            {
                const bf16x8 a = *(const bf16x8*)(tAb + ((((ks + 3) * 32) + hg * 16) ^ tswz));
                acc2 = MFMA32(a, q3, acc2);
                if (ks + 7 < 16) q3 = Bp2[((ks + 7) * 4 + cg2) * 64];
            }
        }
    }

    // ---- o write (relu + fce_b) into [32K,48K): dead A region, disjoint from t ----
    {
        const float fb = fce_b[0];
        #pragma unroll
        for (int r = 0; r < 16; ++r) {
            const int orow = rg * 32 + (r & 3) + 8 * (r >> 2) + 4 * hg;
            const int oc2 = (cg2 * 32 + lrow32) * 2;
            *(short*)(lds + 32768 + (orow << 8) + (oc2 ^ ((orow & 15) << 4))) =
                f2bf(fmaxf(acc2[r] + fb, 0.0f));
        }
    }
    __syncthreads();

    // ---- towers: wave w: rows (w>>1)*16..+15, task w&1 ----
    {
        const int rtt = w >> 1, ct = w & 1;
        f32x4 h = (f32x4){0.f, 0.f, 0.f, 0.f};
        char* oAb = lds + 32768 + ((rtt * 16 + lrow16) << 8);
        const int oswz = (lrow16 & 15) << 4;
        const short* bT = tw1T + (ct * 16 + lrow16) * SBO + lg4 * 8;
        #pragma unroll
        for (int kc = 0; kc < 4; ++kc) {
            const bf16x8 av = *(const bf16x8*)(oAb + ((kc * 64 + lg4 * 16) ^ oswz));
            const bf16x8 bv = *(const bf16x8*)(bT + kc * 32);
            h = __builtin_amdgcn_mfma_f32_16x16x32_bf16(av, bv, h, 0, 0, 0);
        }
        const float b1v = tb1[ct * THD + lrow16];
        const float w2v = tw2[ct * THD + lrow16];
        float p[4];
        #pragma unroll
        for (int rr = 0; rr < 4; ++rr) {
            p[rr] = fmaxf(h[rr] + b1v, 0.0f) * w2v;
            #pragma unroll
            for (int off = 8; off >= 1; off >>= 1)
                p[rr] += __shfl_xor(p[rr], off);
        }
        if (lrow16 == 0) {
            const float b2v = tb2[ct];
            #pragma unroll
            for (int rr = 0; rr < 4; ++rr) {
                const int rowo = rtt * 16 + lg4 * 4 + rr;
                outp[ct * B_ROWS + rowbase + rowo] = 1.0f / (1.0f + __expf(-(p[rr] + b2v)));
            }
        }
    }

    // ---- regularizer (block 0) ----
    if (blockIdx.x == 0 && tid < 64) {
        int s = 0;
        for (int i = tid; i < ACCD + SBH; i += 64) s += regparts[i];
        #pragma unroll
        for (int off = 32; off > 0; off >>= 1) s += __shfl_down(s, off);
        if (tid == 0) outp[NT * B_ROWS] = 1e-4f * (float)s;
    }
}

extern "C" void kernel_launch(void* const* d_in, const int* in_sizes, int n_in,
                              void* d_out, int out_size, void* d_ws, size_t ws_size,
                              hipStream_t stream) {
    const int*   x      = (const int*)d_in[0];
    const float* emb    = (const float*)d_in[1];
    const float* alpha1 = (const float*)d_in[2];
    const float* u1     = (const float*)d_in[3];
    const float* w1     = (const float*)d_in[4];
    const float* alpha2 = (const float*)d_in[5];
    const float* u2     = (const float*)d_in[6];
    const float* w2     = (const float*)d_in[7];
    const float* fce_w  = (const float*)d_in[8];
    const float* fce_b  = (const float*)d_in[9];
    const float* tw1    = (const float*)d_in[10];
    const float* tb1    = (const float*)d_in[11];
    const float* tw2    = (const float*)d_in[12];
    const float* tb2    = (const float*)d_in[13];
    float* outp = (float*)d_out;

    short* W1cF = (short*)d_ws;                       // 131072 shorts
    short* W2F  = W1cF + 32 * 8 * 64 * 8;             // 32768 shorts
    short* tw1T = W2F + 16 * 4 * 64 * 8;              // [32][128]
    int*   regparts = (int*)(tw1T + NT * THD * SBO);  // [768]

    k_prep<<<641, 256, 0, stream>>>(u1, w1, alpha1, fce_w, u2, w2, alpha2, tw1,
                                    W1cF, W2F, tw1T, regparts);
    k_main<<<B_ROWS / ROWS, THR, 0, stream>>>(x, emb, W1cF, W2F, tw1T, fce_b,
                                              tb1, tw2, tb2, regparts, outp);
}

// Round 6
// 123.016 us; speedup vs baseline: 2.7911x; 1.0274x over previous
//
#include <hip/hip_runtime.h>
#include <hip/hip_bf16.h>
#include <math.h>

#define B_ROWS 16384
#define NCOLS 32
#define EDIM 16
#define ACCD 512
#define NE 8
#define SBH 256
#define SBO 128
#define THD 16
#define NT 2

#define ROWS 32
#define THR 512

typedef __attribute__((ext_vector_type(8))) short bf16x8;
typedef __attribute__((ext_vector_type(4))) float f32x4;
typedef __attribute__((ext_vector_type(16))) float f32x16;

__device__ __forceinline__ short f2bf(float f) {
    unsigned u = __float_as_uint(f);
    unsigned r = (u + 0x7FFFu + ((u >> 16) & 1u)) >> 16;   // RNE
    return (short)r;
}

__device__ __forceinline__ bf16x8 pack8(float4 a, float4 b) {
    bf16x8 v;
    v[0] = f2bf(a.x); v[1] = f2bf(a.y); v[2] = f2bf(a.z); v[3] = f2bf(a.w);
    v[4] = f2bf(b.x); v[5] = f2bf(b.y); v[6] = f2bf(b.z); v[7] = f2bf(b.w);
    return v;
}

// ws: W1cF 256KB bf16 (32x32 frag-linear) | W2F 64KB bf16 (16x16 frag-linear) |
//     tw1T [32][128] bf16 | regparts int[768]
// W1cF frag (ks 0..31, cg 0..7): lane l -> col=cg*32+(l&31), k=ks*16+(l>>5)*8+j
// W2F  frag (ks 0..7,  cg 0..7): lane l -> col=cg*16+(l&15), k=ks*32+(l>>4)*8+j

__global__ __launch_bounds__(256) void k_prep(const float* __restrict__ u1,
                                              const float* __restrict__ w1,
                                              const float* __restrict__ alpha1,
                                              const float* __restrict__ fce_w,
                                              const float* __restrict__ u2,
                                              const float* __restrict__ w2,
                                              const float* __restrict__ alpha2,
                                              const float* __restrict__ tw1,
                                              short* __restrict__ W1cF,
                                              short* __restrict__ W2F,
                                              short* __restrict__ tw1T,
                                              int* __restrict__ regparts) {
    const int bid = blockIdx.x;
    const int tid = threadIdx.x;
    if (bid < 512) {
        const int a = bid, c = tid;         // a = k-index, c = col
        const float A = expf(-logf(alpha1[0]) * (1.0f / 0.9f));
        __shared__ int cnts[NE];
        if (c < NE) cnts[c] = 0;
        __syncthreads();
        float acc = 0.0f;
        #pragma unroll
        for (int n = 0; n < NE; ++n) {
            const int idx = (a * NE + n) * SBH + c;
            const float u = u1[idx];
            const float s = u / (u + (1.0f - u) * A);
            const float s_ = s * 2.1f - 0.1f;
            const float z = fminf(fmaxf(s_, 0.0f), 1.0f);
            acc += z * w1[idx] * fce_w[n];
            unsigned long long m = __ballot(s_ < 0.0f);
            if ((c & 63) == 0) atomicAdd(&cnts[n], __popcll(m));
        }
        __syncthreads();
        {
            const int ks = a >> 4, kr = a & 15;
            const int sub = kr >> 3, j = kr & 7;
            const int cg = c >> 5, lane = (sub << 5) | (c & 31);
            W1cF[(((ks * 8 + cg) * 64) + lane) * 8 + j] = f2bf(acc);
        }
        if (c == 0) {
            int tot = 0;
            #pragma unroll
            for (int n = 0; n < NE; ++n) tot += 1 - cnts[n] / NE;   // // NE (shape[1])
            regparts[a] = tot;
        }
    } else if (bid < 640) {
        const int c = (bid - 512) * 2 + (tid >> 7);   // k-index 0..255
        const int d = tid & 127;                      // col
        const float A = expf(-logf(alpha2[0]) * (1.0f / 0.9f));
        const int idx = c * SBO + d;
        const float u = u2[idx];
        const float s = u / (u + (1.0f - u) * A);
        const float s_ = s * 2.1f - 0.1f;
        const float z = fminf(fmaxf(s_, 0.0f), 1.0f);
        {
            const int ks = c >> 5, krem = c & 31;
            const int sub = krem >> 3, j = krem & 7;
            const int cg = d >> 4, lane = (sub << 4) | (d & 15);
            W2F[(((ks * 8 + cg) * 64) + lane) * 8 + j] = f2bf(z * w2[idx]);
        }
        __shared__ int cnts2[2];
        if (tid < 2) cnts2[tid] = 0;
        __syncthreads();
        unsigned long long m = __ballot(s_ < 0.0f);
        if ((tid & 63) == 0) atomicAdd(&cnts2[tid >> 7], __popcll(m));
        __syncthreads();
        if ((tid & 127) == 0) regparts[ACCD + c] = 1 - cnts2[tid >> 7] / SBO;  // // SBO
    } else {
        #pragma unroll
        for (int i = 0; i < 16; ++i) {
            const int e = tid * 16 + i;          // 4096 = 32*128
            const int jj = e >> 7;               // t*16+j
            const int d = e & 127;
            tw1T[jj * SBO + d] = f2bf(tw1[((jj >> 4) * SBO + d) * THD + (jj & 15)]);
        }
    }
}

#define MFMA32(a, b, c) __builtin_amdgcn_mfma_f32_32x32x16_bf16((a), (b), (c), 0, 0, 0)
#define MFMA16(a, b, c) __builtin_amdgcn_mfma_f32_16x16x32_bf16((a), (b), (c), 0, 0, 0)

// LDS: A[32][512] bf16 @0 (32KB) | t[32][256] bf16 @32K (16KB) | o[32][128] bf16 @48K (8KB)
#define LDS_T 32768
#define LDS_O 49152

__global__ __launch_bounds__(THR, 4) void k_main(const int* __restrict__ x,
                                                 const float* __restrict__ emb,
                                                 const short* __restrict__ W1cF,
                                                 const short* __restrict__ W2F,
                                                 const short* __restrict__ tw1T,
                                                 const float* __restrict__ fce_b,
                                                 const float* __restrict__ tb1,
                                                 const float* __restrict__ tw2,
                                                 const float* __restrict__ tb2,
                                                 const int* __restrict__ regparts,
                                                 float* __restrict__ outp) {
    __shared__ __align__(16) char lds[57344];

    const int tid = threadIdx.x;
    const int l = tid & 63;
    const int w = tid >> 6;
    const int lrow32 = l & 31;
    const int hg = l >> 5;
    const int lrow16 = l & 15;
    const int lg4 = (l >> 4) & 3;
    const int rowbase = blockIdx.x * ROWS;

    // ---- staging roles: one emb row (64B) per thread per K-half ----
    const int srow = tid >> 4;           // 0..31
    const int scol = tid & 15;           // 0..15
    char* sbase = lds + (srow << 10);
    const int sswz = (srow & 15) << 4;

    const int xv0 = x[(rowbase + srow) * NCOLS + scol];
    const int xv1 = x[(rowbase + srow) * NCOLS + 16 + scol];

    {   // half 0 stage
        const float4* ep = reinterpret_cast<const float4*>(emb + (size_t)xv0 * EDIM);
        const float4 e0 = ep[0], e1 = ep[1], e2 = ep[2], e3 = ep[3];
        *(bf16x8*)(sbase + ((scol * 32 + 0) ^ sswz))  = pack8(e0, e1);
        *(bf16x8*)(sbase + ((scol * 32 + 16) ^ sswz)) = pack8(e2, e3);
    }
    // half 1: issue loads EARLY (regs), LDS-write after GEMM1-half0 (T14)
    const float4* ep1 = reinterpret_cast<const float4*>(emb + (size_t)xv1 * EDIM);
    const float4 g0 = ep1[0], g1 = ep1[1], g2 = ep1[2], g3 = ep1[3];
    __syncthreads();

    // ---- GEMM1: t[32][256] = xf[32][512] x W1c[512][256]; wave w -> cols w*32..+31 ----
    char* aAb = lds + (lrow32 << 10);
    const int aswz = (lrow32 & 15) << 4;
    const bf16x8* Bp = ((const bf16x8*)W1cF) + l;

    f32x16 acc;
    #pragma unroll
    for (int i = 0; i < 16; ++i) acc[i] = 0.0f;

    bf16x8 b0 = Bp[(0 * 8 + w) * 64];
    bf16x8 b1 = Bp[(1 * 8 + w) * 64];
    bf16x8 b2 = Bp[(2 * 8 + w) * 64];
    bf16x8 b3 = Bp[(3 * 8 + w) * 64];

    #pragma unroll
    for (int ks = 0; ks < 16; ks += 4) {
        { const bf16x8 a = *(const bf16x8*)(aAb + ((((ks + 0) * 32) + hg * 16) ^ aswz));
          acc = MFMA32(a, b0, acc); b0 = Bp[((ks + 4) * 8 + w) * 64]; }
        { const bf16x8 a = *(const bf16x8*)(aAb + ((((ks + 1) * 32) + hg * 16) ^ aswz));
          acc = MFMA32(a, b1, acc); b1 = Bp[((ks + 5) * 8 + w) * 64]; }
        { const bf16x8 a = *(const bf16x8*)(aAb + ((((ks + 2) * 32) + hg * 16) ^ aswz));
          acc = MFMA32(a, b2, acc); b2 = Bp[((ks + 6) * 8 + w) * 64]; }
        { const bf16x8 a = *(const bf16x8*)(aAb + ((((ks + 3) * 32) + hg * 16) ^ aswz));
          acc = MFMA32(a, b3, acc); b3 = Bp[((ks + 7) * 8 + w) * 64]; }
    }
    // write half 1 (loads were issued before half-0 loop)
    *(bf16x8*)(sbase + (((16 + scol) * 32 + 0) ^ sswz))  = pack8(g0, g1);
    *(bf16x8*)(sbase + (((16 + scol) * 32 + 16) ^ sswz)) = pack8(g2, g3);
    __syncthreads();

    #pragma unroll
    for (int ks = 16; ks < 32; ks += 4) {
        { const bf16x8 a = *(const bf16x8*)(aAb + ((((ks + 0) * 32) + hg * 16) ^ aswz));
          acc = MFMA32(a, b0, acc); if (ks + 4 < 32) b0 = Bp[((ks + 4) * 8 + w) * 64]; }
        { const bf16x8 a = *(const bf16x8*)(aAb + ((((ks + 1) * 32) + hg * 16) ^ aswz));
          acc = MFMA32(a, b1, acc); if (ks + 5 < 32) b1 = Bp[((ks + 5) * 8 + w) * 64]; }
        { const bf16x8 a = *(const bf16x8*)(aAb + ((((ks + 2) * 32) + hg * 16) ^ aswz));
          acc = MFMA32(a, b2, acc); if (ks + 6 < 32) b2 = Bp[((ks + 6) * 8 + w) * 64]; }
        { const bf16x8 a = *(const bf16x8*)(aAb + ((((ks + 3) * 32) + hg * 16) ^ aswz));
          acc = MFMA32(a, b3, acc); if (ks + 7 < 32) b3 = Bp[((ks + 7) * 8 + w) * 64]; }
    }

    // ---- GEMM2 B prefetch (issued before t-barrier) ----
    const int cgA = (w & 3) * 2;
    const int rg2 = w >> 2;
    const bf16x8* Bp2 = ((const bf16x8*)W2F) + l;
    bf16x8 q0a = Bp2[(0 * 8 + cgA) * 64], q0b = Bp2[(0 * 8 + cgA + 1) * 64];
    bf16x8 q1a = Bp2[(1 * 8 + cgA) * 64], q1b = Bp2[(1 * 8 + cgA + 1) * 64];

    // ---- t write (bf16 swizzled). D(32x32): col=l&31, row=(r&3)+8*(r>>2)+4*hg ----
    {
        const int tcol2 = (w * 32 + lrow32) * 2;
        #pragma unroll
        for (int r = 0; r < 16; ++r) {
            const int trow = (r & 3) + 8 * (r >> 2) + 4 * hg;
            *(short*)(lds + LDS_T + (trow << 9) + (tcol2 ^ ((trow & 15) << 4))) = f2bf(acc[r]);
        }
    }
    __syncthreads();

    // ---- GEMM2: o[32][128] = t[32][256] x W2eff[256][128]; wave: rows rg2*16, cols cgA*16..+31 ----
    f32x4 acc2[2];
    acc2[0] = (f32x4){0.f, 0.f, 0.f, 0.f};
    acc2[1] = (f32x4){0.f, 0.f, 0.f, 0.f};
    {
        char* tAb = lds + LDS_T + ((rg2 * 16 + lrow16) << 9);
        const int tswz = (lrow16 & 15) << 4;
        #pragma unroll
        for (int kc = 0; kc < 8; kc += 2) {
            { const bf16x8 a = *(const bf16x8*)(tAb + ((((kc + 0) * 64) + lg4 * 16) ^ tswz));
              acc2[0] = MFMA16(a, q0a, acc2[0]);
              acc2[1] = MFMA16(a, q0b, acc2[1]);
              if (kc + 2 < 8) { q0a = Bp2[((kc + 2) * 8 + cgA) * 64]; q0b = Bp2[((kc + 2) * 8 + cgA + 1) * 64]; } }
            { const bf16x8 a = *(const bf16x8*)(tAb + ((((kc + 1) * 64) + lg4 * 16) ^ tswz));
              acc2[0] = MFMA16(a, q1a, acc2[0]);
              acc2[1] = MFMA16(a, q1b, acc2[1]);
              if (kc + 3 < 8) { q1a = Bp2[((kc + 3) * 8 + cgA) * 64]; q1b = Bp2[((kc + 3) * 8 + cgA + 1) * 64]; } }
        }
    }

    // ---- o write (relu + fce_b). D(16x16): col=l&15, row=lg4*4+r ----
    {
        const float fb = fce_b[0];
        #pragma unroll
        for (int fd = 0; fd < 2; ++fd) {
            const int d2 = ((cgA + fd) * 16 + lrow16) * 2;
            #pragma unroll
            for (int rr = 0; rr < 4; ++rr) {
                const int orow = rg2 * 16 + lg4 * 4 + rr;
                *(short*)(lds + LDS_O + (orow << 8) + (d2 ^ ((orow & 15) << 4))) =
                    f2bf(fmaxf(acc2[fd][rr] + fb, 0.0f));
            }
        }
    }
    __syncthreads();

    // ---- towers: waves 0..3: rows (w>>1)*16..+15, task w&1 ----
    if (w < 4) {
        const int rtt = w >> 1, ct = w & 1;
        f32x4 h = (f32x4){0.f, 0.f, 0.f, 0.f};
        char* oAb = lds + LDS_O + ((rtt * 16 + lrow16) << 8);
        const int oswz = (lrow16 & 15) << 4;
        const short* bT = tw1T + (ct * 16 + lrow16) * SBO + lg4 * 8;
        #pragma unroll
        for (int kc = 0; kc < 4; ++kc) {
            const bf16x8 av = *(const bf16x8*)(oAb + ((kc * 64 + lg4 * 16) ^ oswz));
            const bf16x8 bv = *(const bf16x8*)(bT + kc * 32);
            h = MFMA16(av, bv, h);
        }
        const float b1v = tb1[ct * THD + lrow16];
        const float w2v = tw2[ct * THD + lrow16];
        float p[4];
        #pragma unroll
        for (int rr = 0; rr < 4; ++rr) {
            p[rr] = fmaxf(h[rr] + b1v, 0.0f) * w2v;
            #pragma unroll
            for (int off = 8; off >= 1; off >>= 1)
                p[rr] += __shfl_xor(p[rr], off);
        }
        if (lrow16 == 0) {
            const float b2v = tb2[ct];
            #pragma unroll
            for (int rr = 0; rr < 4; ++rr) {
                const int rowo = rtt * 16 + lg4 * 4 + rr;
                outp[ct * B_ROWS + rowbase + rowo] = 1.0f / (1.0f + __expf(-(p[rr] + b2v)));
            }
        }
    }

    // ---- regularizer (block 0) ----
    if (blockIdx.x == 0 && tid < 64) {
        int s = 0;
        for (int i = tid; i < ACCD + SBH; i += 64) s += regparts[i];
        #pragma unroll
        for (int off = 32; off > 0; off >>= 1) s += __shfl_down(s, off);
        if (tid == 0) outp[NT * B_ROWS] = 1e-4f * (float)s;
    }
}

extern "C" void kernel_launch(void* const* d_in, const int* in_sizes, int n_in,
                              void* d_out, int out_size, void* d_ws, size_t ws_size,
                              hipStream_t stream) {
    const int*   x      = (const int*)d_in[0];
    const float* emb    = (const float*)d_in[1];
    const float* alpha1 = (const float*)d_in[2];
    const float* u1     = (const float*)d_in[3];
    const float* w1     = (const float*)d_in[4];
    const float* alpha2 = (const float*)d_in[5];
    const float* u2     = (const float*)d_in[6];
    const float* w2     = (const float*)d_in[7];
    const float* fce_w  = (const float*)d_in[8];
    const float* fce_b  = (const float*)d_in[9];
    const float* tw1    = (const float*)d_in[10];
    const float* tb1    = (const float*)d_in[11];
    const float* tw2    = (const float*)d_in[12];
    const float* tb2    = (const float*)d_in[13];
    float* outp = (float*)d_out;

    short* W1cF = (short*)d_ws;                       // 131072 shorts
    short* W2F  = W1cF + 32 * 8 * 64 * 8;             // 32768 shorts
    short* tw1T = W2F + 8 * 8 * 64 * 8;               // [32][128]
    int*   regparts = (int*)(tw1T + NT * THD * SBO);  // [768]

    k_prep<<<641, 256, 0, stream>>>(u1, w1, alpha1, fce_w, u2, w2, alpha2, tw1,
                                    W1cF, W2F, tw1T, regparts);
    k_main<<<B_ROWS / ROWS, THR, 0, stream>>>(x, emb, W1cF, W2F, tw1T, fce_b,
                                              tb1, tw2, tb2, regparts, outp);
}